// Round 8
// baseline (220.521 us; speedup 1.0000x reference)
//
#include <hip/hip_runtime.h>
#include <hip/hip_bf16.h>
#include <stdint.h>

#define M_POS 0.5f
#define M_NEG 0.1f
#define LAM_NEG 1.0f

typedef __attribute__((ext_vector_type(4))) float floatx4;  // 16x16 MFMA accumulator
typedef __attribute__((ext_vector_type(8))) int   intx8;    // 32B fp8 operand (K=128)
typedef __attribute__((ext_vector_type(4))) int   int32x4;

union Frag8 { intx8 v; int4 q[2]; };

// ---------------- Kernel A: row sumsq, inv_norm, fp32 -> fp8(e4m3) quantize, zero accs ----
__global__ __launch_bounds__(256) void prep_kernel(
    const float* __restrict__ cb, unsigned char* __restrict__ cb_q,
    float* __restrict__ sq, float* __restrict__ inv_norm,
    unsigned* __restrict__ zero_base, int zero_len,
    int N, int d)
{
    const int gi = blockIdx.x * 256 + threadIdx.x;
    if (gi < zero_len) zero_base[gi] = 0u;

    const int t = threadIdx.x;
    const int w = t >> 6, l = t & 63;
    const int row = blockIdx.x * 4 + w;
    if (row >= N) return;
    const float* src = cb + (size_t)row * d;
    unsigned char* dst = cb_q + (size_t)row * d;

    float s = 0.f;
    for (int c = l * 16; c < d; c += 1024) {
        float4 v0 = *(const float4*)(src + c);
        float4 v1 = *(const float4*)(src + c + 4);
        float4 v2 = *(const float4*)(src + c + 8);
        float4 v3 = *(const float4*)(src + c + 12);
        s += v0.x*v0.x + v0.y*v0.y + v0.z*v0.z + v0.w*v0.w
           + v1.x*v1.x + v1.y*v1.y + v1.z*v1.z + v1.w*v1.w
           + v2.x*v2.x + v2.y*v2.y + v2.z*v2.z + v2.w*v2.w
           + v3.x*v3.x + v3.y*v3.y + v3.z*v3.z + v3.w*v3.w;
        int p0 = __builtin_amdgcn_cvt_pk_fp8_f32(v0.x, v0.y, 0, false);
        p0     = __builtin_amdgcn_cvt_pk_fp8_f32(v0.z, v0.w, p0, true);
        int p1 = __builtin_amdgcn_cvt_pk_fp8_f32(v1.x, v1.y, 0, false);
        p1     = __builtin_amdgcn_cvt_pk_fp8_f32(v1.z, v1.w, p1, true);
        int p2 = __builtin_amdgcn_cvt_pk_fp8_f32(v2.x, v2.y, 0, false);
        p2     = __builtin_amdgcn_cvt_pk_fp8_f32(v2.z, v2.w, p2, true);
        int p3 = __builtin_amdgcn_cvt_pk_fp8_f32(v3.x, v3.y, 0, false);
        p3     = __builtin_amdgcn_cvt_pk_fp8_f32(v3.z, v3.w, p3, true);
        int32x4 pk; pk.x = p0; pk.y = p1; pk.z = p2; pk.w = p3;
        *(int32x4*)(dst + c) = pk;
    }
    for (int o = 32; o > 0; o >>= 1) s += __shfl_down(s, o, 64);
    if (l == 0) { sq[row] = s; inv_norm[row] = rsqrtf(s); }
}

// ---------------- Kernel B: fused symmetric MX-fp8 Gram GEMM + loss epilogue + finalize ----
// R23 = R21 loop (dbuf + counted vmcnt; == R22's fancy phase-split, both 129.5us) +
// CLUSTER-ORDERED TILE MAP + DIAG B-ALIAS. Diagnosis: block lifetime L=43us == staging
// service time (512KB @ ~5 B/cy/CU from L3/HBM), runtime = 3 rounds x L (528 blocks,
// 1 blk/CU — REGISTER-FORCED: 8 waves x (128 VGPR + 128 acc) = 2048 = full CU file, so
// no co-residency is possible at 256^2 and schedule tweaks are null, R21==R22).
// FETCH=46MB vs 8.4MB input: the old contiguous-vt triangular map gives high-bx XCDs
// all-32-A-strip footprints (8.4MB >> 4MB L2) -> staging misses L2, served ~3 TB/s.
// Fix: enumerate tiles super-tile-major (supers = 8by x 4bx tiles = 12 strips = 3MB,
// L2-resident), supers in (bxs,bys) lex order; each XCD's contiguous 66-rank slice is
// then spatially compact. Diag tiles alias B := A (skip B staging; vmcnt 4 not 8).
// Canary: FETCH_SIZE must drop to ~15-28MB. If it drops and time doesn't: service BW
// wasn't the L-driver. If it doesn't drop: blockIdx%%8->XCD dispatch model is wrong.
// DO-NOTs: phase-split/distributed-restage (R22: null); all 128^2 variants (R15-R20);
// builtin/asm reg prefetch (R18/R19); deep-ring 1blk 4-wave (R20); per-thread fences.
__global__ __launch_bounds__(512, 1) void gram_loss_kernel(
    const unsigned char* __restrict__ A,   // N x d fp8, row-major
    const float* __restrict__ sq, const float* __restrict__ inv_norm,
    const int* __restrict__ starts, const int* __restrict__ ends,
    const int* __restrict__ max_ip,
    float* __restrict__ pos_acc, float* __restrict__ neg_acc,
    unsigned* __restrict__ counter, float* __restrict__ out,
    int N, int d)
{
    const int M = min(N, max_ip[0] + 1);

    // XCD slice remap: contiguous ranks per XCD (528 % 8 == 0 -> 66 ranks/XCD).
    int vt = blockIdx.x;
    const int nB = gridDim.x;
    if ((nB & 7) == 0) {
        const int per = nB >> 3;
        vt = (blockIdx.x & 7) * per + (blockIdx.x >> 3);
    }

    // cluster-ordered triangular decode: supers of 8(by) x 4(bx) tiles, (bxs,bys) lex.
    // Bijection rank -> (by,bx), by <= bx. nb=32 assumed (N=8192); generic fallback below.
    int by = -1, bx = -1;
    const int nb = N / 256;
    if (nb == 32) {
        int rem = vt;
        for (int bxs = 0; bxs < 8 && by < 0; ++bxs) {
            const int hi = bxs * 4 + 3;
            for (int bys = 0; bys <= (bxs >> 1) && by < 0; ++bys) {
                int cnt = 0;
#pragma unroll
                for (int r = 0; r < 8; ++r) {
                    const int byy = bys * 8 + r;
                    const int lo = max(byy, bxs * 4);
                    cnt += max(0, hi - lo + 1);
                }
                if (rem >= cnt) { rem -= cnt; continue; }
                for (int r = 0; r < 8; ++r) {
                    const int byy = bys * 8 + r;
                    const int lo = max(byy, bxs * 4);
                    const int c = max(0, hi - lo + 1);
                    if (rem < c) { by = byy; bx = lo + rem; break; }
                    rem -= c;
                }
            }
        }
    } else {
        // generic triangular decode (unused at N=8192)
        bx = (int)((sqrtf(8.f * (float)vt + 1.f) - 1.f) * 0.5f);
        while ((bx + 1) * (bx + 2) / 2 <= vt) bx++;
        while (bx * (bx + 1) / 2 > vt) bx--;
        by = vt - bx * (bx + 1) / 2;
    }

    const int rowBase = by * 256;
    const int colBase = bx * 256;
    const bool isDiag = (by == bx);

    // double-buffered 256-row x 128-byte K-tiles: 2 x (32KB A + 32KB B) = 128KB
    __shared__ alignas(16) unsigned char ldsA[2][256 * 128];
    __shared__ alignas(16) unsigned char ldsB[2][256 * 128];

    const int tid  = threadIdx.x;
    const int wave = tid >> 6;
    const int lane = tid & 63;
    const int wr = (wave >> 2) * 128;   // M-half
    const int wc = (wave & 3) * 64;     // N-quarter

    floatx4 acc[8][4];
#pragma unroll
    for (int a = 0; a < 8; ++a)
#pragma unroll
        for (int b = 0; b < 4; ++b) acc[a][b] = (floatx4){0.f, 0.f, 0.f, 0.f};

    // staging geometry (verified R21/R22): 512 threads cover 64 rows/issue;
    // dst lane-linear, src chunk xor-swizzled.
    const int sRow8 = tid >> 3;
    const int sChk  = tid & 7;
    const int srcOffC = ((sChk ^ (sRow8 & 7)) * 16);
    const int kTiles = d / 128;                        // 8

    // fragment-read constants (verified)
    const int rl = lane & 15;
    const int g  = lane >> 4;
    const int rx = rl & 7;
    const int c0 = (((2 * g)     ^ rx) * 16);
    const int c1 = (((2 * g + 1) ^ rx) * 16);

#define STAGE(SLOT, KT)                                                         \
    { const int k0_ = (KT) * 128;                                               \
      _Pragma("unroll")                                                         \
      for (int h = 0; h < 4; ++h) {                                             \
        const int r_ = h * 64 + sRow8;                                          \
        const unsigned char* ga_ = A + (size_t)(rowBase + r_) * d + k0_ + srcOffC; \
        __builtin_amdgcn_global_load_lds(                                       \
            (const __attribute__((address_space(1))) void*)ga_,                 \
            (__attribute__((address_space(3))) void*)(ldsA[SLOT] + r_ * 128 + sChk * 16), 16, 0, 0); \
      }                                                                         \
      if (!isDiag) {                                                            \
        _Pragma("unroll")                                                       \
        for (int h = 0; h < 4; ++h) {                                           \
          const int r_ = h * 64 + sRow8;                                        \
          const unsigned char* gb_ = A + (size_t)(colBase + r_) * d + k0_ + srcOffC; \
          __builtin_amdgcn_global_load_lds(                                     \
              (const __attribute__((address_space(1))) void*)gb_,               \
              (__attribute__((address_space(3))) void*)(ldsB[SLOT] + r_ * 128 + sChk * 16), 16, 0, 0); \
        }                                                                       \
      } }

#define WAITV(NN)  asm volatile("s_waitcnt vmcnt(" #NN ")" ::: "memory")

    {
        STAGE(0, 0)
        __builtin_amdgcn_sched_barrier(0);
        STAGE(1, 1)
        __builtin_amdgcn_sched_barrier(0);

        for (int kt = 0; kt < kTiles; ++kt) {
            const int cur = kt & 1;
            // kt's loads retired; kt+1's stay in flight (8 nondiag / 4 diag per thread)
            if (kt < kTiles - 1) {
                if (isDiag) { WAITV(4); } else { WAITV(8); }
            } else {
                WAITV(0);
            }
            __builtin_amdgcn_s_barrier();              // buf[cur] complete for all waves

            const unsigned char* bbase = isDiag ? ldsA[cur] : ldsB[cur];
            Frag8 bfr[4];
#pragma unroll
            for (int ct = 0; ct < 4; ++ct) {
                const unsigned char* pb = bbase + (wc + ct * 16 + rl) * 128;
                bfr[ct].q[0] = *(const int4*)(pb + c0);
                bfr[ct].q[1] = *(const int4*)(pb + c1);
            }
            __builtin_amdgcn_s_setprio(1);
#pragma unroll
            for (int rt = 0; rt < 8; ++rt) {
                Frag8 af;
                const unsigned char* pa = ldsA[cur] + (wr + rt * 16 + rl) * 128;
                af.q[0] = *(const int4*)(pa + c0);
                af.q[1] = *(const int4*)(pa + c1);
#pragma unroll
                for (int ct = 0; ct < 4; ++ct)
                    acc[rt][ct] = __builtin_amdgcn_mfma_scale_f32_16x16x128_f8f6f4(
                        af.v, bfr[ct].v, acc[rt][ct], 0, 0, 0, 127, 0, 127);
            }
            __builtin_amdgcn_s_setprio(0);
            __builtin_amdgcn_sched_barrier(0);

            __builtin_amdgcn_s_barrier();              // all waves done reading buf[cur]
            if (kt + 2 < kTiles) {
                STAGE(cur, kt + 2)                     // refill; in flight across next kt
                __builtin_amdgcn_sched_barrier(0);
            }
        }
    }
#undef STAGE
#undef WAITV

    // ---- epilogue (16x16 C/D: col=lane&15, row=(lane>>4)*4+reg) ----
    const int q  = lane >> 4;
    const int jlo = colBase + wc;
    const int ilo = rowBase + wr;

    int   jn[4];
    float jinv[4];
    bool  jvalid[4];
#pragma unroll
    for (int ct = 0; ct < 4; ++ct) {
        const int j = jlo + ct * 16 + rl;
        jn[ct]  = j;
        jinv[ct] = inv_norm[j];
        jvalid[ct] = (j < M);
    }

    // wave-uniform positive-pair possibility check over the wave's 128-row x 64-col tile
    bool posLane = false;
    {
        const int ri0 = ilo + lane;
        const int ri1 = ilo + 64 + lane;
        if (ri0 < M) posLane |= (ends[ri0] >= jlo) && (starts[ri0] <= jlo + 63);
        if (ri1 < M) posLane |= (ends[ri1] >= jlo) && (starts[ri1] <= jlo + 63);
        if (!isDiag) {
            const int cj = jlo + lane;
            if (cj < M) posLane |= (ends[cj] >= ilo) && (starts[cj] <= ilo + 127);
        }
    }
    const bool fullPath = (__ballot(posLane) != 0ULL);

    float posc[4] = {0.f, 0.f, 0.f, 0.f};
    float negc[4] = {0.f, 0.f, 0.f, 0.f};

    if (fullPath) {
        int   jns[4], jne[4];
        float jsq[4];
#pragma unroll
        for (int ct = 0; ct < 4; ++ct) {
            jsq[ct] = sq[jn[ct]];
            jns[ct] = jvalid[ct] ? starts[jn[ct]] : 0;
            jne[ct] = jvalid[ct] ? ends[jn[ct]]   : -1;
        }
#pragma unroll
        for (int rt = 0; rt < 8; ++rt) {
            const int ibase = ilo + rt * 16 + q * 4;
#pragma unroll
            for (int reg = 0; reg < 4; ++reg) {
                const int i = ibase + reg;
                const bool rowValid = (i < M);
                const int ns = rowValid ? starts[i] : 0;
                const int ne = rowValid ? ends[i]   : -1;
                const float iinv = inv_norm[i];
                const float isq  = sq[i];
                float posp = 0.f, negp = 0.f;
#pragma unroll
                for (int ct = 0; ct < 4; ++ct) {
                    const float dot = acc[rt][ct][reg];
                    const int j = jn[ct];
                    float cosv = dot * iinv * jinv[ct];
                    cosv = fminf(fmaxf(cosv, -1.f), 1.f);
                    float tn = fmaxf(fabsf(cosv) - M_NEG, 0.f);
                    const float nterm = tn * tn;
                    const float d2 = fmaxf(isq + jsq[ct] - 2.f * dot, 0.f);
                    float tp = fmaxf(sqrtf(d2) - M_POS, 0.f);
                    const float pterm = tp * tp;
                    const bool dg = (j == i);
                    if (rowValid) {
                        const bool in_r = (j >= ns) && (j <= ne);
                        if (in_r && !dg) posp += pterm;
                        if (!in_r || dg) negp += nterm;
                    }
                    if (!isDiag && jvalid[ct]) {
                        const bool in_c = (i >= jns[ct]) && (i <= jne[ct]);
                        if (in_c && !dg) posc[ct] += pterm;
                        if (!in_c || dg) negc[ct] += nterm;
                    }
                }
#pragma unroll
                for (int m = 1; m < 16; m <<= 1) {
                    posp += __shfl_xor(posp, m, 64);
                    negp += __shfl_xor(negp, m, 64);
                }
                if (rowValid && rl == 0) {
                    atomicAdd(&pos_acc[i], posp);
                    atomicAdd(&neg_acc[i], negp);
                }
            }
        }
        if (!isDiag) {
#pragma unroll
            for (int ct = 0; ct < 4; ++ct) {
                posc[ct] += __shfl_xor(posc[ct], 16, 64);
                posc[ct] += __shfl_xor(posc[ct], 32, 64);
                negc[ct] += __shfl_xor(negc[ct], 16, 64);
                negc[ct] += __shfl_xor(negc[ct], 32, 64);
            }
            if (q == 0) {
#pragma unroll
                for (int ct = 0; ct < 4; ++ct) {
                    if (jvalid[ct]) {
                        atomicAdd(&pos_acc[jn[ct]], posc[ct]);
                        atomicAdd(&neg_acc[jn[ct]], negc[ct]);
                    }
                }
            }
        }
    } else {
        // fast path: every element is a negative for both its row and its column
#pragma unroll
        for (int rt = 0; rt < 8; ++rt) {
            const int ibase = ilo + rt * 16 + q * 4;
#pragma unroll
            for (int reg = 0; reg < 4; ++reg) {
                const int i = ibase + reg;
                const float iinv = inv_norm[i];
                float negp = 0.f;
#pragma unroll
                for (int ct = 0; ct < 4; ++ct) {
                    const float dot = acc[rt][ct][reg];
                    float cosv = dot * iinv * jinv[ct];
                    cosv = fminf(fmaxf(cosv, -1.f), 1.f);
                    float tn = fmaxf(fabsf(cosv) - M_NEG, 0.f);
                    const float nterm = tn * tn;
                    negp += nterm;
                    negc[ct] += nterm;
                }
#pragma unroll
                for (int m = 1; m < 16; m <<= 1)
                    negp += __shfl_xor(negp, m, 64);
                if ((i < M) && rl == 0)
                    atomicAdd(&neg_acc[i], negp);
            }
        }
        if (!isDiag) {
#pragma unroll
            for (int ct = 0; ct < 4; ++ct) {
                negc[ct] += __shfl_xor(negc[ct], 16, 64);
                negc[ct] += __shfl_xor(negc[ct], 32, 64);
            }
            if (q == 0) {
#pragma unroll
                for (int ct = 0; ct < 4; ++ct)
                    if (jvalid[ct])
                        atomicAdd(&neg_acc[jn[ct]], negc[ct]);
            }
        }
    }

    // ---- last-block finalize (fence/atomic by tid0 only — validated R7) ----
    struct FinSm { int amLast; float ts[8]; int cs[8]; };
    FinSm* fs = (FinSm*)&ldsA[0][0];
    __syncthreads();
    if (tid == 0) {
        __threadfence();
        unsigned old = atomicAdd(counter, 1u);
        fs->amLast = (old == (unsigned)(gridDim.x - 1)) ? 1 : 0;
    }
    __syncthreads();
    if (fs->amLast) {
        __threadfence();
        float total = 0.f;
        int cnt = 0;
        for (int i = tid; i < M; i += 512) {
            const float pa = __hip_atomic_load(&pos_acc[i], __ATOMIC_RELAXED, __HIP_MEMORY_SCOPE_AGENT);
            const float na = __hip_atomic_load(&neg_acc[i], __ATOMIC_RELAXED, __HIP_MEMORY_SCOPE_AGENT);
            const int ns = starts[i], ne = ends[i];
            const int lo = max(ns, 0), hi = min(ne, N - 1);
            const int inr = max(hi - lo + 1, 0);
            const bool dg = (i >= ns) && (i <= ne);
            const int pos_cnt = inr - (dg ? 1 : 0);
            const int neg_cnt = N - inr + (dg ? 1 : 0);
            if (pos_cnt > 0 && neg_cnt > 0) {
                total += pa / (float)max(pos_cnt, 1)
                       + LAM_NEG * na / (float)max(neg_cnt, 1);
                cnt++;
            }
        }
        for (int o = 32; o > 0; o >>= 1) {
            total += __shfl_down(total, o, 64);
            cnt   += __shfl_down(cnt, o, 64);
        }
        if (lane == 0) { fs->ts[wave] = total; fs->cs[wave] = cnt; }
        __syncthreads();
        if (tid == 0) {
            float T = 0.f; int C = 0;
            for (int wv = 0; wv < 8; ++wv) { T += fs->ts[wv]; C += fs->cs[wv]; }
            out[0] = (C > 0) ? T / (float)C : 0.f;
        }
    }
}

extern "C" void kernel_launch(void* const* d_in, const int* in_sizes, int n_in,
                              void* d_out, int out_size, void* d_ws, size_t ws_size,
                              hipStream_t stream) {
    const float* cb     = (const float*)d_in[0];
    const int*   starts = (const int*)d_in[1];
    const int*   ends   = (const int*)d_in[2];
    const int*   max_ip = (const int*)d_in[3];
    float* out = (float*)d_out;

    const int N = in_sizes[1];
    const int d = in_sizes[0] / N;

    char* ws = (char*)d_ws;
    unsigned char* cb_q = (unsigned char*)ws;
    size_t off = ((size_t)N * d + 255) & ~(size_t)255;
    float* sq       = (float*)(ws + off); off += (size_t)N * 4;
    float* inv_norm = (float*)(ws + off); off += (size_t)N * 4;
    float* pos_acc  = (float*)(ws + off); off += (size_t)N * 4;
    float* neg_acc  = (float*)(ws + off); off += (size_t)N * 4;
    unsigned* counter = (unsigned*)(ws + off); off += 256;

    // prep zeroes pos_acc/neg_acc/counter (2N+1 u32, contiguous)
    prep_kernel<<<(N + 3) / 4, 256, 0, stream>>>(cb, cb_q, sq, inv_norm,
                                                 (unsigned*)pos_acc, 2 * N + 1, N, d);

    const int nb = N / 256;
    const int nBlocks = nb * (nb + 1) / 2;   // upper-triangular 256x256 tiles (528 @ N=8192)
    gram_loss_kernel<<<nBlocks, 512, 0, stream>>>(cb_q, sq, inv_norm, starts, ends,
                                                  max_ip, pos_acc, neg_acc, counter,
                                                  out, N, d);
}

// Round 9
// 216.184 us; speedup vs baseline: 1.0201x; 1.0201x over previous
//
#include <hip/hip_runtime.h>
#include <hip/hip_bf16.h>
#include <stdint.h>

#define M_POS 0.5f
#define M_NEG 0.1f
#define LAM_NEG 1.0f

typedef __attribute__((ext_vector_type(4))) float floatx4;  // 16x16 MFMA accumulator
typedef __attribute__((ext_vector_type(8))) int   intx8;    // 32B fp8 operand (K=128)
typedef __attribute__((ext_vector_type(4))) int   int32x4;

union Frag8 { intx8 v; int4 q[2]; };

// ---------------- Kernel A: row sumsq, inv_norm, fp32 -> fp8(e4m3) quantize, zero accs ----
__global__ __launch_bounds__(256) void prep_kernel(
    const float* __restrict__ cb, unsigned char* __restrict__ cb_q,
    float* __restrict__ sq, float* __restrict__ inv_norm,
    unsigned* __restrict__ zero_base, int zero_len,
    int N, int d)
{
    const int gi = blockIdx.x * 256 + threadIdx.x;
    if (gi < zero_len) zero_base[gi] = 0u;

    const int t = threadIdx.x;
    const int w = t >> 6, l = t & 63;
    const int row = blockIdx.x * 4 + w;
    if (row >= N) return;
    const float* src = cb + (size_t)row * d;
    unsigned char* dst = cb_q + (size_t)row * d;

    float s = 0.f;
    for (int c = l * 16; c < d; c += 1024) {
        float4 v0 = *(const float4*)(src + c);
        float4 v1 = *(const float4*)(src + c + 4);
        float4 v2 = *(const float4*)(src + c + 8);
        float4 v3 = *(const float4*)(src + c + 12);
        s += v0.x*v0.x + v0.y*v0.y + v0.z*v0.z + v0.w*v0.w
           + v1.x*v1.x + v1.y*v1.y + v1.z*v1.z + v1.w*v1.w
           + v2.x*v2.x + v2.y*v2.y + v2.z*v2.z + v2.w*v2.w
           + v3.x*v3.x + v3.y*v3.y + v3.z*v3.z + v3.w*v3.w;
        int p0 = __builtin_amdgcn_cvt_pk_fp8_f32(v0.x, v0.y, 0, false);
        p0     = __builtin_amdgcn_cvt_pk_fp8_f32(v0.z, v0.w, p0, true);
        int p1 = __builtin_amdgcn_cvt_pk_fp8_f32(v1.x, v1.y, 0, false);
        p1     = __builtin_amdgcn_cvt_pk_fp8_f32(v1.z, v1.w, p1, true);
        int p2 = __builtin_amdgcn_cvt_pk_fp8_f32(v2.x, v2.y, 0, false);
        p2     = __builtin_amdgcn_cvt_pk_fp8_f32(v2.z, v2.w, p2, true);
        int p3 = __builtin_amdgcn_cvt_pk_fp8_f32(v3.x, v3.y, 0, false);
        p3     = __builtin_amdgcn_cvt_pk_fp8_f32(v3.z, v3.w, p3, true);
        int32x4 pk; pk.x = p0; pk.y = p1; pk.z = p2; pk.w = p3;
        *(int32x4*)(dst + c) = pk;
    }
    for (int o = 32; o > 0; o >>= 1) s += __shfl_down(s, o, 64);
    if (l == 0) { sq[row] = s; inv_norm[row] = rsqrtf(s); }
}

// ---------------- Kernel B: fused symmetric MX-fp8 Gram GEMM + loss epilogue + finalize ----
// R24 = R21's K-loop (dbuf + counted vmcnt, 129.5us, == R22's phase-split) + MULTI-TILE
// PERSISTENT BLOCKS. Evidence: 1 blk/CU (register-forced) means ZERO inter-block overlap
// per CU; runtime = 3.0 x 43us block lifetime vs 2.06 rounds ideal -- a full extra round
// lost to serial cold prologues. Fix: grid = 256 (1 block/CU exact), each block runs
// 2-3 CONSECUTIVE by-major ranks (240x2 + 16x3): (a) consecutive ranks share the A-panel
// -> 2nd/3rd tile's A staging is L1/L2-hot (FETCH canary: 46 -> ~30MB); (b) next tile's
// 16 prologue loads issue BEFORE the current epilogue (LDS free after K-loop's final
// barrier) -> inter-tile drain hides under 4-6us of epilogue VALU/atomics. FIFO vmcnt
// analysis: epilogue vmem ops are always NEWER than pre-staged loads, so WAITV(8)
// (leaves newest 8 outstanding) still guarantees the needed LDS buffer resident.
// DO-NOTs: super-tile cluster order + diag B-alias (R23: 145us regression); phase-split
// distributed restage (R22: null vs R21); all 128^2 schedule variants (R15-R20);
// builtin/asm reg prefetch (R18/R19); deep ring 4-wave (R20); per-thread fences (R3).
__global__ __launch_bounds__(512, 1) void gram_loss_kernel(
    const unsigned char* __restrict__ A,   // N x d fp8, row-major
    const float* __restrict__ sq, const float* __restrict__ inv_norm,
    const int* __restrict__ starts, const int* __restrict__ ends,
    const int* __restrict__ max_ip,
    float* __restrict__ pos_acc, float* __restrict__ neg_acc,
    unsigned* __restrict__ counter, float* __restrict__ out,
    int N, int d)
{
    const int M = min(N, max_ip[0] + 1);
    const int nb = N / 256;
    const int T  = nb * (nb + 1) / 2;      // total triangular tiles (528 @ N=8192)
    const int G  = gridDim.x;

    // XCD-compact block remap: XCD k hosts contiguous chunk range -> compact rank span.
    int b = blockIdx.x;
    if ((G & 7) == 0) {
        const int per = G >> 3;
        b = (blockIdx.x & 7) * per + (blockIdx.x >> 3);
    }
    // contiguous chunk of ranks for this block: q or q+1 tiles
    const int q0 = T / G, r0 = T % G;
    const int start = b * q0 + min(b, r0);
    const int cnt   = q0 + (b < r0 ? 1 : 0);

    // double-buffered 256-row x 128-byte K-tiles: 2 x (32KB A + 32KB B) = 128KB
    __shared__ alignas(16) unsigned char ldsA[2][256 * 128];
    __shared__ alignas(16) unsigned char ldsB[2][256 * 128];

    const int tid  = threadIdx.x;
    const int wave = tid >> 6;
    const int lane = tid & 63;
    const int wr = (wave >> 2) * 128;   // M-half
    const int wc = (wave & 3) * 64;     // N-quarter

    // staging geometry (verified R21/R22): 512 threads cover 64 rows/issue;
    // dst lane-linear, src chunk xor-swizzled.
    const int sRow8 = tid >> 3;
    const int sChk  = tid & 7;
    const int srcOffC = ((sChk ^ (sRow8 & 7)) * 16);
    const int kTiles = d / 128;                        // 8

    // fragment-read constants (verified)
    const int rl = lane & 15;
    const int g  = lane >> 4;
    const int rx = rl & 7;
    const int c0 = (((2 * g)     ^ rx) * 16);
    const int c1 = (((2 * g + 1) ^ rx) * 16);

#define STAGE_RC(SLOT, KT, ROWB, COLB)                                          \
    { const int k0_ = (KT) * 128;                                               \
      _Pragma("unroll")                                                         \
      for (int h = 0; h < 4; ++h) {                                             \
        const int r_ = h * 64 + sRow8;                                          \
        const unsigned char* ga_ = A + (size_t)((ROWB) + r_) * d + k0_ + srcOffC; \
        __builtin_amdgcn_global_load_lds(                                       \
            (const __attribute__((address_space(1))) void*)ga_,                 \
            (__attribute__((address_space(3))) void*)(ldsA[SLOT] + r_ * 128 + sChk * 16), 16, 0, 0); \
        const unsigned char* gb_ = A + (size_t)((COLB) + r_) * d + k0_ + srcOffC; \
        __builtin_amdgcn_global_load_lds(                                       \
            (const __attribute__((address_space(1))) void*)gb_,                 \
            (__attribute__((address_space(3))) void*)(ldsB[SLOT] + r_ * 128 + sChk * 16), 16, 0, 0); \
      } }

#define WAITV(NN)  asm volatile("s_waitcnt vmcnt(" #NN ")" ::: "memory")
#define SCHED0     __builtin_amdgcn_sched_barrier(0)

    // decode first rank (by-major: row by has nb-by tiles; consecutive ranks share by)
    int byC = 0;
    {
        int rem = start;
        while (byC < nb && rem >= nb - byC) { rem -= nb - byC; ++byC; }
        byC = (cnt > 0) ? byC : 0;
        // bxC computed below from remainder; recompute cleanly:
    }
    int bxC;
    {
        int rem = start, byT = 0;
        while (byT < nb && rem >= nb - byT) { rem -= nb - byT; ++byT; }
        byC = byT; bxC = byT + rem;
    }

    if (cnt > 0) {
        // prologue for first tile
        STAGE_RC(0, 0, byC * 256, bxC * 256) SCHED0;
        STAGE_RC(1, 1, byC * 256, bxC * 256) SCHED0;
    }

    for (int s = 0; s < cnt; ++s) {
        const int rowBase = byC * 256;
        const int colBase = bxC * 256;
        const bool isDiag = (byC == bxC);

        floatx4 acc[8][4];
#pragma unroll
        for (int a = 0; a < 8; ++a)
#pragma unroll
            for (int bq = 0; bq < 4; ++bq) acc[a][bq] = (floatx4){0.f, 0.f, 0.f, 0.f};

        for (int kt = 0; kt < kTiles; ++kt) {
            const int cur = kt & 1;
            // kt's loads retired; kt+1's (the 8 newest vmem ops) stay in flight.
            // For s>0, stray epilogue vmem ops are OLDER than this tile's staging,
            // so WAITV(8) (<=8 outstanding) still retires everything kt needs.
            if (kt < kTiles - 1) { WAITV(8); } else { WAITV(0); }
            __builtin_amdgcn_s_barrier();              // buf[cur] complete for all waves

            Frag8 bfr[4];
#pragma unroll
            for (int ct = 0; ct < 4; ++ct) {
                const unsigned char* pb = ldsB[cur] + (wc + ct * 16 + rl) * 128;
                bfr[ct].q[0] = *(const int4*)(pb + c0);
                bfr[ct].q[1] = *(const int4*)(pb + c1);
            }
            __builtin_amdgcn_s_setprio(1);
#pragma unroll
            for (int rt = 0; rt < 8; ++rt) {
                Frag8 af;
                const unsigned char* pa = ldsA[cur] + (wr + rt * 16 + rl) * 128;
                af.q[0] = *(const int4*)(pa + c0);
                af.q[1] = *(const int4*)(pa + c1);
#pragma unroll
                for (int ct = 0; ct < 4; ++ct)
                    acc[rt][ct] = __builtin_amdgcn_mfma_scale_f32_16x16x128_f8f6f4(
                        af.v, bfr[ct].v, acc[rt][ct], 0, 0, 0, 127, 0, 127);
            }
            __builtin_amdgcn_s_setprio(0);
            SCHED0;

            __builtin_amdgcn_s_barrier();              // all waves done reading buf[cur]
            if (kt + 2 < kTiles) {
                STAGE_RC(cur, kt + 2, rowBase, colBase)  // refill; in flight across next kt
                SCHED0;
            }
        }

        // ---- pre-stage NEXT tile's first two K-chunks (LDS free after final barrier);
        //      these loads hide under the epilogue below ----
        int byN = byC, bxN = bxC;
        if (s + 1 < cnt) {
            bxN = bxC + 1;
            if (bxN >= nb) { byN = byC + 1; bxN = byN; }   // by-major successor
            STAGE_RC(0, 0, byN * 256, bxN * 256) SCHED0;
            STAGE_RC(1, 1, byN * 256, bxN * 256) SCHED0;
        }

        // ---- epilogue (16x16 C/D: col=lane&15, row=(lane>>4)*4+reg) ----
        const int qq  = lane >> 4;
        const int jlo = colBase + wc;
        const int ilo = rowBase + wr;

        int   jn[4];
        float jinv[4];
        bool  jvalid[4];
#pragma unroll
        for (int ct = 0; ct < 4; ++ct) {
            const int j = jlo + ct * 16 + rl;
            jn[ct]  = j;
            jinv[ct] = inv_norm[j];
            jvalid[ct] = (j < M);
        }

        // wave-uniform positive-pair possibility check over the wave's 128x64 tile
        bool posLane = false;
        {
            const int ri0 = ilo + lane;
            const int ri1 = ilo + 64 + lane;
            if (ri0 < M) posLane |= (ends[ri0] >= jlo) && (starts[ri0] <= jlo + 63);
            if (ri1 < M) posLane |= (ends[ri1] >= jlo) && (starts[ri1] <= jlo + 63);
            if (!isDiag) {
                const int cj = jlo + lane;
                if (cj < M) posLane |= (ends[cj] >= ilo) && (starts[cj] <= ilo + 127);
            }
        }
        const bool fullPath = (__ballot(posLane) != 0ULL);

        float posc[4] = {0.f, 0.f, 0.f, 0.f};
        float negc[4] = {0.f, 0.f, 0.f, 0.f};

        if (fullPath) {
            int   jns[4], jne[4];
            float jsq[4];
#pragma unroll
            for (int ct = 0; ct < 4; ++ct) {
                jsq[ct] = sq[jn[ct]];
                jns[ct] = jvalid[ct] ? starts[jn[ct]] : 0;
                jne[ct] = jvalid[ct] ? ends[jn[ct]]   : -1;
            }
#pragma unroll
            for (int rt = 0; rt < 8; ++rt) {
                const int ibase = ilo + rt * 16 + qq * 4;
#pragma unroll
                for (int reg = 0; reg < 4; ++reg) {
                    const int i = ibase + reg;
                    const bool rowValid = (i < M);
                    const int ns = rowValid ? starts[i] : 0;
                    const int ne = rowValid ? ends[i]   : -1;
                    const float iinv = inv_norm[i];
                    const float isq  = sq[i];
                    float posp = 0.f, negp = 0.f;
#pragma unroll
                    for (int ct = 0; ct < 4; ++ct) {
                        const float dot = acc[rt][ct][reg];
                        const int j = jn[ct];
                        float cosv = dot * iinv * jinv[ct];
                        cosv = fminf(fmaxf(cosv, -1.f), 1.f);
                        float tn = fmaxf(fabsf(cosv) - M_NEG, 0.f);
                        const float nterm = tn * tn;
                        const float d2 = fmaxf(isq + jsq[ct] - 2.f * dot, 0.f);
                        float tp = fmaxf(sqrtf(d2) - M_POS, 0.f);
                        const float pterm = tp * tp;
                        const bool dg = (j == i);
                        if (rowValid) {
                            const bool in_r = (j >= ns) && (j <= ne);
                            if (in_r && !dg) posp += pterm;
                            if (!in_r || dg) negp += nterm;
                        }
                        if (!isDiag && jvalid[ct]) {
                            const bool in_c = (i >= jns[ct]) && (i <= jne[ct]);
                            if (in_c && !dg) posc[ct] += pterm;
                            if (!in_c || dg) negc[ct] += nterm;
                        }
                    }
#pragma unroll
                    for (int m = 1; m < 16; m <<= 1) {
                        posp += __shfl_xor(posp, m, 64);
                        negp += __shfl_xor(negp, m, 64);
                    }
                    if (rowValid && rl == 0) {
                        atomicAdd(&pos_acc[i], posp);
                        atomicAdd(&neg_acc[i], negp);
                    }
                }
            }
            if (!isDiag) {
#pragma unroll
                for (int ct = 0; ct < 4; ++ct) {
                    posc[ct] += __shfl_xor(posc[ct], 16, 64);
                    posc[ct] += __shfl_xor(posc[ct], 32, 64);
                    negc[ct] += __shfl_xor(negc[ct], 16, 64);
                    negc[ct] += __shfl_xor(negc[ct], 32, 64);
                }
                if (qq == 0) {
#pragma unroll
                    for (int ct = 0; ct < 4; ++ct) {
                        if (jvalid[ct]) {
                            atomicAdd(&pos_acc[jn[ct]], posc[ct]);
                            atomicAdd(&neg_acc[jn[ct]], negc[ct]);
                        }
                    }
                }
            }
        } else {
            // fast path: every element is a negative for both its row and its column
#pragma unroll
            for (int rt = 0; rt < 8; ++rt) {
                const int ibase = ilo + rt * 16 + qq * 4;
#pragma unroll
                for (int reg = 0; reg < 4; ++reg) {
                    const int i = ibase + reg;
                    const float iinv = inv_norm[i];
                    float negp = 0.f;
#pragma unroll
                    for (int ct = 0; ct < 4; ++ct) {
                        const float dot = acc[rt][ct][reg];
                        float cosv = dot * iinv * jinv[ct];
                        cosv = fminf(fmaxf(cosv, -1.f), 1.f);
                        float tn = fmaxf(fabsf(cosv) - M_NEG, 0.f);
                        const float nterm = tn * tn;
                        negp += nterm;
                        negc[ct] += nterm;
                    }
#pragma unroll
                    for (int m = 1; m < 16; m <<= 1)
                        negp += __shfl_xor(negp, m, 64);
                    if ((i < M) && rl == 0)
                        atomicAdd(&neg_acc[i], negp);
                }
            }
            if (!isDiag) {
#pragma unroll
                for (int ct = 0; ct < 4; ++ct) {
                    negc[ct] += __shfl_xor(negc[ct], 16, 64);
                    negc[ct] += __shfl_xor(negc[ct], 32, 64);
                }
                if (qq == 0) {
#pragma unroll
                    for (int ct = 0; ct < 4; ++ct)
                        if (jvalid[ct])
                            atomicAdd(&neg_acc[jn[ct]], negc[ct]);
                }
            }
        }

        byC = byN; bxC = bxN;
    }
#undef STAGE_RC
#undef WAITV
#undef SCHED0

    // ---- last-block finalize (fence/atomic by tid0 only — validated R7) ----
    struct FinSm { int amLast; float ts[8]; int cs[8]; };
    FinSm* fs = (FinSm*)&ldsA[0][0];
    __syncthreads();
    if (tid == 0) {
        __threadfence();
        unsigned old = atomicAdd(counter, 1u);
        fs->amLast = (old == (unsigned)(gridDim.x - 1)) ? 1 : 0;
    }
    __syncthreads();
    if (fs->amLast) {
        __threadfence();
        float total = 0.f;
        int cntv = 0;
        for (int i = tid; i < M; i += 512) {
            const float pa = __hip_atomic_load(&pos_acc[i], __ATOMIC_RELAXED, __HIP_MEMORY_SCOPE_AGENT);
            const float na = __hip_atomic_load(&neg_acc[i], __ATOMIC_RELAXED, __HIP_MEMORY_SCOPE_AGENT);
            const int ns = starts[i], ne = ends[i];
            const int lo = max(ns, 0), hi = min(ne, N - 1);
            const int inr = max(hi - lo + 1, 0);
            const bool dg = (i >= ns) && (i <= ne);
            const int pos_cnt = inr - (dg ? 1 : 0);
            const int neg_cnt = N - inr + (dg ? 1 : 0);
            if (pos_cnt > 0 && neg_cnt > 0) {
                total += pa / (float)max(pos_cnt, 1)
                       + LAM_NEG * na / (float)max(neg_cnt, 1);
                cntv++;
            }
        }
        for (int o = 32; o > 0; o >>= 1) {
            total += __shfl_down(total, o, 64);
            cntv  += __shfl_down(cntv, o, 64);
        }
        if (lane == 0) { fs->ts[wave] = total; fs->cs[wave] = cntv; }
        __syncthreads();
        if (tid == 0) {
            float Tt = 0.f; int C = 0;
            for (int wv = 0; wv < 8; ++wv) { Tt += fs->ts[wv]; C += fs->cs[wv]; }
            out[0] = (C > 0) ? Tt / (float)C : 0.f;
        }
    }
}

extern "C" void kernel_launch(void* const* d_in, const int* in_sizes, int n_in,
                              void* d_out, int out_size, void* d_ws, size_t ws_size,
                              hipStream_t stream) {
    const float* cb     = (const float*)d_in[0];
    const int*   starts = (const int*)d_in[1];
    const int*   ends   = (const int*)d_in[2];
    const int*   max_ip = (const int*)d_in[3];
    float* out = (float*)d_out;

    const int N = in_sizes[1];
    const int d = in_sizes[0] / N;

    char* ws = (char*)d_ws;
    unsigned char* cb_q = (unsigned char*)ws;
    size_t off = ((size_t)N * d + 255) & ~(size_t)255;
    float* sq       = (float*)(ws + off); off += (size_t)N * 4;
    float* inv_norm = (float*)(ws + off); off += (size_t)N * 4;
    float* pos_acc  = (float*)(ws + off); off += (size_t)N * 4;
    float* neg_acc  = (float*)(ws + off); off += (size_t)N * 4;
    unsigned* counter = (unsigned*)(ws + off); off += 256;

    // prep zeroes pos_acc/neg_acc/counter (2N+1 u32, contiguous)
    prep_kernel<<<(N + 3) / 4, 256, 0, stream>>>(cb, cb_q, sq, inv_norm,
                                                 (unsigned*)pos_acc, 2 * N + 1, N, d);

    const int nb = N / 256;
    const int T  = nb * (nb + 1) / 2;        // 528 triangular tiles @ N=8192
    const int G  = (T < 256) ? T : 256;      // persistent-style: one block per CU
    gram_loss_kernel<<<G, 512, 0, stream>>>(cb_q, sq, inv_norm, starts, ends,
                                            max_ip, pos_acc, neg_acc, counter,
                                            out, N, d);
}